// Round 2
// baseline (728.841 us; speedup 1.0000x reference)
//
#include <hip/hip_runtime.h>
#include <math.h>

// Problem constants (from reference): B=16, N=4096, H=2048, fp32.
constexpr int B = 16;
constexpr int N = 4096;
constexpr int H = 2048;

constexpr int BLOCKS_PER_BATCH = 64;                     // 1024 blocks total = 4 blocks/CU
constexpr int WAVES_PER_BLOCK  = 4;                      // 256 threads
constexpr int WAVES_PER_BATCH  = BLOCKS_PER_BATCH * WAVES_PER_BLOCK; // 256
constexpr int ROWS_PER_WAVE    = N / WAVES_PER_BATCH;    // 16
constexpr int F4_PER_ROW       = H / 4;                  // 512 float4 per row
constexpr int F4_PER_LANE      = F4_PER_ROW / 64;        // 8 float4 per lane

constexpr float kInvScale = 0.022097086912079608f;       // 1/sqrt(2048)

// Pass 1: one wave = 16 rows, online softmax, row stays in registers between
// QK^T dot and PV accumulate -> outputs[] is read from HBM exactly once.
// 16 waves/CU (launch_bounds 256,4) for latency hiding of the serial
// load->shuffle-reduce->exp->accumulate chain.
__global__ __launch_bounds__(256, 4) void attn_pass1(
    const float* __restrict__ outs,      // [B, N, H]
    const float* __restrict__ last_h,    // [B, H]
    float* __restrict__ ws_logits,       // [B, N]
    float* __restrict__ ws_m,            // [B, WAVES_PER_BATCH]
    float* __restrict__ ws_l,            // [B, WAVES_PER_BATCH]
    float* __restrict__ ws_ctx)          // [B, WAVES_PER_BATCH, H]
{
    const int b    = blockIdx.x / BLOCKS_PER_BATCH;
    const int blk  = blockIdx.x % BLOCKS_PER_BATCH;
    const int wave = threadIdx.x >> 6;
    const int lane = threadIdx.x & 63;
    const int wid  = blk * WAVES_PER_BLOCK + wave;  // 0..255 within batch
    const int row0 = wid * ROWS_PER_WAVE;

    // q fragment: lane holds float4s {lane + 64*j}
    const float4* q4 = reinterpret_cast<const float4*>(last_h + (size_t)b * H);
    float4 q[F4_PER_LANE];
#pragma unroll
    for (int j = 0; j < F4_PER_LANE; ++j) q[j] = q4[lane + 64 * j];

    float4 ctx[F4_PER_LANE];
#pragma unroll
    for (int j = 0; j < F4_PER_LANE; ++j) ctx[j] = make_float4(0.f, 0.f, 0.f, 0.f);
    float m = -INFINITY;
    float l = 0.f;

    const float4* krow = reinterpret_cast<const float4*>(outs) +
                         ((size_t)b * N + row0) * F4_PER_ROW;

    for (int r = 0; r < ROWS_PER_WAVE; ++r) {
        float4 k[F4_PER_LANE];
#pragma unroll
        for (int j = 0; j < F4_PER_LANE; ++j) k[j] = krow[lane + 64 * j];
        krow += F4_PER_ROW;

        float s = 0.f;
#pragma unroll
        for (int j = 0; j < F4_PER_LANE; ++j)
            s += k[j].x * q[j].x + k[j].y * q[j].y + k[j].z * q[j].z + k[j].w * q[j].w;
        // wave-64 butterfly reduce; all lanes end with full dot
#pragma unroll
        for (int off = 32; off > 0; off >>= 1) s += __shfl_xor(s, off, 64);
        s *= kInvScale;

        if (lane == 0) ws_logits[(size_t)b * N + row0 + r] = s;

        if (s > m) {                    // wave-uniform branch
            const float corr = __expf(m - s);   // m==-inf -> 0 (first row ok)
            l *= corr;
#pragma unroll
            for (int j = 0; j < F4_PER_LANE; ++j) {
                ctx[j].x *= corr; ctx[j].y *= corr;
                ctx[j].z *= corr; ctx[j].w *= corr;
            }
            m = s;
        }
        const float w = __expf(s - m);
        l += w;
#pragma unroll
        for (int j = 0; j < F4_PER_LANE; ++j) {
            ctx[j].x += w * k[j].x; ctx[j].y += w * k[j].y;
            ctx[j].z += w * k[j].z; ctx[j].w += w * k[j].w;
        }
    }

    const int gw = b * WAVES_PER_BATCH + wid;
    if (lane == 0) { ws_m[gw] = m; ws_l[gw] = l; }
    float4* cdst = reinterpret_cast<float4*>(ws_ctx) + (size_t)gw * F4_PER_ROW;
#pragma unroll
    for (int j = 0; j < F4_PER_LANE; ++j) cdst[lane + 64 * j] = ctx[j];
}

// Pass 2: 8 blocks per batch.
//   part 0..3 : ctx combine, f4-slice of 128, threads split 256 partials in 2 halves
//   part 4..7 : attn = exp(logit - M)/L over an n-slice of 1024
__global__ __launch_bounds__(256) void attn_pass2(
    const float* __restrict__ ws_logits,
    const float* __restrict__ ws_m,
    const float* __restrict__ ws_l,
    const float* __restrict__ ws_ctx,
    float* __restrict__ out_ctx,         // [B, H]
    float* __restrict__ out_attn)        // [B, N]
{
    __shared__ float lm[WAVES_PER_BATCH];
    __shared__ float lscale[WAVES_PER_BATCH];
    __shared__ float lsl[WAVES_PER_BATCH];
    __shared__ float4 red[128];

    const int bid  = blockIdx.x;
    const int b    = bid >> 3;
    const int part = bid & 7;
    const int tid  = threadIdx.x;

    const float mw = ws_m[b * WAVES_PER_BATCH + tid];
    const float lw = ws_l[b * WAVES_PER_BATCH + tid];
    lm[tid] = mw;
    __syncthreads();

    float M = -INFINITY;
    for (int w = 0; w < WAVES_PER_BATCH; ++w) M = fmaxf(M, lm[w]);

    const float sc = __expf(mw - M);
    lscale[tid] = sc;
    lsl[tid]    = sc * lw;
    __syncthreads();

    float L = 0.f;
    for (int w = 0; w < WAVES_PER_BATCH; ++w) L += lsl[w];
    const float invL = 1.f / L;

    if (part < 4) {
        // ctx combine: f4 index = part*128 + (tid&127); w-half = tid>>7
        const int f  = part * 128 + (tid & 127);
        const int wh = tid >> 7;
        const float4* c4 = reinterpret_cast<const float4*>(ws_ctx) +
                           (size_t)b * WAVES_PER_BATCH * F4_PER_ROW;
        float4 acc = make_float4(0.f, 0.f, 0.f, 0.f);
        for (int w = wh * 128; w < wh * 128 + 128; ++w) {
            const float s = lscale[w];
            const float4 v = c4[(size_t)w * F4_PER_ROW + f];
            acc.x += s * v.x; acc.y += s * v.y;
            acc.z += s * v.z; acc.w += s * v.w;
        }
        if (wh == 1) red[tid & 127] = acc;
        __syncthreads();
        if (wh == 0) {
            const float4 o = red[tid];
            float4* o4 = reinterpret_cast<float4*>(out_ctx) + (size_t)b * F4_PER_ROW;
            o4[f] = make_float4((acc.x + o.x) * invL, (acc.y + o.y) * invL,
                                (acc.z + o.z) * invL, (acc.w + o.w) * invL);
        }
    } else {
        const int n0 = (part - 4) * 1024;
#pragma unroll
        for (int i = 0; i < 4; ++i) {
            const int n = n0 + i * 256 + tid;
            out_attn[(size_t)b * N + n] =
                __expf(ws_logits[(size_t)b * N + n] - M) * invL;
        }
    }
}

extern "C" void kernel_launch(void* const* d_in, const int* in_sizes, int n_in,
                              void* d_out, int out_size, void* d_ws, size_t ws_size,
                              hipStream_t stream) {
    const float* outs   = (const float*)d_in[0];   // [B, N, H]
    const float* last_h = (const float*)d_in[1];   // [B, H]

    float* out_ctx  = (float*)d_out;                 // [B, H]
    float* out_attn = (float*)d_out + (size_t)B * H; // [B, N]

    float* ws        = (float*)d_ws;
    float* ws_logits = ws;                                   // B*N
    float* ws_m      = ws_logits + (size_t)B * N;            // B*256
    float* ws_l      = ws_m + (size_t)B * WAVES_PER_BATCH;   // B*256
    float* ws_ctx    = ws_l + (size_t)B * WAVES_PER_BATCH;   // B*256*H (32 MiB)

    attn_pass1<<<B * BLOCKS_PER_BATCH, 256, 0, stream>>>(
        outs, last_h, ws_logits, ws_m, ws_l, ws_ctx);
    attn_pass2<<<B * 8, 256, 0, stream>>>(
        ws_logits, ws_m, ws_l, ws_ctx, out_ctx, out_attn);
}

// Round 3
// 650.440 us; speedup vs baseline: 1.1205x; 1.1205x over previous
//
#include <hip/hip_runtime.h>
#include <math.h>

// Problem constants (from reference): B=16, N=4096, H=2048, fp32.
constexpr int B = 16;
constexpr int N = 4096;
constexpr int H = 2048;

constexpr int BLOCKS_PER_BATCH = 32;                     // 512 blocks = 2 blocks/CU
constexpr int WAVES_PER_BLOCK  = 4;                      // 256 threads
constexpr int WAVES_PER_BATCH  = BLOCKS_PER_BATCH * WAVES_PER_BLOCK; // 128
constexpr int ROWS_PER_WAVE    = N / WAVES_PER_BATCH;    // 32
constexpr int F4_PER_ROW       = H / 4;                  // 512 float4 per row
constexpr int F4_PER_LANE      = F4_PER_ROW / 64;        // 8 float4 per lane
constexpr int PARTIALS         = BLOCKS_PER_BATCH;       // 32 ctx partials per batch

constexpr float kInvScale = 0.022097086912079608f;       // 1/sqrt(2048)

typedef float vf4 __attribute__((ext_vector_type(4)));

__device__ __forceinline__ vf4 ntload(const vf4* p) {
    return __builtin_nontemporal_load(p);
}

// Pass 1: one wave = 32 rows, online softmax, row stays in registers between
// QK^T dot and PV accumulate -> outputs[] read from HBM exactly once,
// non-temporally (no reuse; don't thrash L2/L3). Block-level LDS combine
// shrinks ctx partials to one per block (32/batch).
__global__ __launch_bounds__(256, 2) void attn_pass1(
    const float* __restrict__ outs,      // [B, N, H]
    const float* __restrict__ last_h,    // [B, H]
    float* __restrict__ ws_logits,       // [B, N]
    float* __restrict__ ws_m,            // [B, PARTIALS]
    float* __restrict__ ws_l,            // [B, PARTIALS]
    float* __restrict__ ws_ctx)          // [B, PARTIALS, H]
{
    __shared__ float lm[WAVES_PER_BLOCK];
    __shared__ float ll[WAVES_PER_BLOCK];
    __shared__ vf4   lctx[WAVES_PER_BLOCK][F4_PER_ROW];  // 32 KiB

    const int b    = blockIdx.x / BLOCKS_PER_BATCH;
    const int blk  = blockIdx.x % BLOCKS_PER_BATCH;
    const int wave = threadIdx.x >> 6;
    const int lane = threadIdx.x & 63;
    const int wid  = blk * WAVES_PER_BLOCK + wave;  // 0..127 within batch
    const int row0 = wid * ROWS_PER_WAVE;

    // q fragment: lane holds float4s {lane + 64*j}
    const vf4* q4 = reinterpret_cast<const vf4*>(last_h + (size_t)b * H);
    vf4 q[F4_PER_LANE];
#pragma unroll
    for (int j = 0; j < F4_PER_LANE; ++j) q[j] = q4[lane + 64 * j];

    vf4 ctx[F4_PER_LANE];
#pragma unroll
    for (int j = 0; j < F4_PER_LANE; ++j) ctx[j] = (vf4){0.f, 0.f, 0.f, 0.f};
    float m = -INFINITY;
    float l = 0.f;

    const vf4* krow = reinterpret_cast<const vf4*>(outs) +
                      ((size_t)b * N + row0) * F4_PER_ROW;

    for (int r = 0; r < ROWS_PER_WAVE; ++r) {
        vf4 k[F4_PER_LANE];
#pragma unroll
        for (int j = 0; j < F4_PER_LANE; ++j) k[j] = ntload(&krow[lane + 64 * j]);
        krow += F4_PER_ROW;

        float s = 0.f;
#pragma unroll
        for (int j = 0; j < F4_PER_LANE; ++j)
            s += k[j].x * q[j].x + k[j].y * q[j].y + k[j].z * q[j].z + k[j].w * q[j].w;
        // wave-64 butterfly reduce; all lanes end with full dot
#pragma unroll
        for (int off = 32; off > 0; off >>= 1) s += __shfl_xor(s, off, 64);
        s *= kInvScale;

        if (lane == 0) ws_logits[(size_t)b * N + row0 + r] = s;

        if (s > m) {                    // wave-uniform branch
            const float corr = __expf(m - s);   // m==-inf -> 0 (first row ok)
            l *= corr;
#pragma unroll
            for (int j = 0; j < F4_PER_LANE; ++j) ctx[j] *= corr;
            m = s;
        }
        const float w = __expf(s - m);
        l += w;
#pragma unroll
        for (int j = 0; j < F4_PER_LANE; ++j) ctx[j] += w * k[j];
    }

    // ---- block-level combine across the 4 waves via LDS ----
#pragma unroll
    for (int j = 0; j < F4_PER_LANE; ++j) lctx[wave][lane + 64 * j] = ctx[j];
    if (lane == 0) { lm[wave] = m; ll[wave] = l; }
    __syncthreads();

    const float m0 = lm[0], m1 = lm[1], m2 = lm[2], m3 = lm[3];
    const float Mb = fmaxf(fmaxf(m0, m1), fmaxf(m2, m3));
    const float s0 = __expf(m0 - Mb), s1 = __expf(m1 - Mb),
                s2 = __expf(m2 - Mb), s3 = __expf(m3 - Mb);
    const float Lb = s0 * ll[0] + s1 * ll[1] + s2 * ll[2] + s3 * ll[3];

    const int gp = b * PARTIALS + blk;
    vf4* cdst = reinterpret_cast<vf4*>(ws_ctx) + (size_t)gp * F4_PER_ROW;
    const int tid = threadIdx.x;
#pragma unroll
    for (int rep = 0; rep < 2; ++rep) {
        const int f = tid + rep * 256;
        const vf4 acc = s0 * lctx[0][f] + s1 * lctx[1][f] +
                        s2 * lctx[2][f] + s3 * lctx[3][f];
        cdst[f] = acc;
    }
    if (tid == 0) { ws_m[gp] = Mb; ws_l[gp] = Lb; }
}

// Pass 2: 8 blocks per batch.
//   part 0..3 : ctx combine over an f4-slice of 128; 256 threads split the
//               32 partials into 2 halves of 16, LDS-reduced.
//   part 4..7 : attn = exp(logit - M)/L over an n-slice of 1024.
__global__ __launch_bounds__(256) void attn_pass2(
    const float* __restrict__ ws_logits,
    const float* __restrict__ ws_m,
    const float* __restrict__ ws_l,
    const float* __restrict__ ws_ctx,
    float* __restrict__ out_ctx,         // [B, H]
    float* __restrict__ out_attn)        // [B, N]
{
    __shared__ float lm[PARTIALS];
    __shared__ float lscale[PARTIALS];
    __shared__ float lsl[PARTIALS];
    __shared__ vf4 red[128];

    const int bid  = blockIdx.x;
    const int b    = bid >> 3;
    const int part = bid & 7;
    const int tid  = threadIdx.x;

    if (tid < PARTIALS) {
        lm[tid] = ws_m[b * PARTIALS + tid];
    }
    __syncthreads();

    float M = -INFINITY;
#pragma unroll
    for (int w = 0; w < PARTIALS; ++w) M = fmaxf(M, lm[w]);

    if (tid < PARTIALS) {
        const float sc = __expf(lm[tid] - M);
        lscale[tid] = sc;
        lsl[tid]    = sc * ws_l[b * PARTIALS + tid];
    }
    __syncthreads();

    float L = 0.f;
#pragma unroll
    for (int w = 0; w < PARTIALS; ++w) L += lsl[w];
    const float invL = 1.f / L;

    if (part < 4) {
        // ctx combine: f4 index = part*128 + (tid&127); partial-half = tid>>7
        const int f  = part * 128 + (tid & 127);
        const int wh = tid >> 7;
        const vf4* c4 = reinterpret_cast<const vf4*>(ws_ctx) +
                        (size_t)b * PARTIALS * F4_PER_ROW;
        vf4 acc = (vf4){0.f, 0.f, 0.f, 0.f};
#pragma unroll
        for (int i = 0; i < 16; ++i) {
            const int w = wh * 16 + i;
            acc += lscale[w] * c4[(size_t)w * F4_PER_ROW + f];
        }
        if (wh == 1) red[tid & 127] = acc;
        __syncthreads();
        if (wh == 0) {
            acc += red[tid];
            vf4* o4 = reinterpret_cast<vf4*>(out_ctx) + (size_t)b * F4_PER_ROW;
            o4[f] = acc * invL;
        }
    } else {
        const int n0 = (part - 4) * 1024;
#pragma unroll
        for (int i = 0; i < 4; ++i) {
            const int n = n0 + i * 256 + tid;
            out_attn[(size_t)b * N + n] =
                __expf(ws_logits[(size_t)b * N + n] - M) * invL;
        }
    }
}

extern "C" void kernel_launch(void* const* d_in, const int* in_sizes, int n_in,
                              void* d_out, int out_size, void* d_ws, size_t ws_size,
                              hipStream_t stream) {
    const float* outs   = (const float*)d_in[0];   // [B, N, H]
    const float* last_h = (const float*)d_in[1];   // [B, H]

    float* out_ctx  = (float*)d_out;                 // [B, H]
    float* out_attn = (float*)d_out + (size_t)B * H; // [B, N]

    float* ws        = (float*)d_ws;
    float* ws_logits = ws;                                   // B*N       (256 KiB)
    float* ws_m      = ws_logits + (size_t)B * N;            // B*32
    float* ws_l      = ws_m + (size_t)B * PARTIALS;          // B*32
    float* ws_ctx    = ws_l + (size_t)B * PARTIALS;          // B*32*H    (4 MiB)

    attn_pass1<<<B * BLOCKS_PER_BATCH, 256, 0, stream>>>(
        outs, last_h, ws_logits, ws_m, ws_l, ws_ctx);
    attn_pass2<<<B * 8, 256, 0, stream>>>(
        ws_logits, ws_m, ws_l, ws_ctx, out_ctx, out_attn);
}